// Round 17
// baseline (261.552 us; speedup 1.0000x reference)
//
#include <hip/hip_runtime.h>
#include <hip/hip_bf16.h>

typedef __attribute__((ext_vector_type(8))) short short8;
typedef __attribute__((ext_vector_type(4))) short short4v;
typedef __attribute__((ext_vector_type(4))) float f32x4;

__device__ inline float bf2f(short s) {
    unsigned u = ((unsigned)(unsigned short)s) << 16;
    float f; __builtin_memcpy(&f, &u, 4); return f;
}
__device__ inline short f2bf(float f) {
    unsigned u; __builtin_memcpy(&u, &f, 4);
    unsigned r = (u + 0x7fffu + ((u >> 16) & 1u)) >> 16;
    return (short)r;
}
__device__ inline float ex2(float x) {
    float r; asm("v_exp_f32 %0, %1" : "=v"(r) : "v"(x)); return r;
}
__device__ inline unsigned cvtpk(float lo, float hi) {
    unsigned r; asm("v_cvt_pk_bf16_f32 %0, %1, %2" : "=v"(r) : "v"(lo), "v"(hi)); return r;
}
__device__ inline float gelu_fast(float x) {
    float xx = x * x;
    float u2 = x * fmaf(0.10294323f, xx, 2.3022085f);
    float t = ex2(u2);
    return x - x * __builtin_amdgcn_rcpf(t + 1.f);
}
template <typename T>
__device__ inline void ntstore(const T& v, T* p) { __builtin_nontemporal_store(v, p); }

#define GLD_LDS16(g, l) __builtin_amdgcn_global_load_lds( \
    (const __attribute__((address_space(1))) void*)(g),   \
    (__attribute__((address_space(3))) void*)(l), 16, 0, 0)

#define BARRIER_PIN do { __builtin_amdgcn_s_barrier(); __builtin_amdgcn_sched_barrier(0); } while (0)

// -------- detect input dtype world + mask encoding (1 block) --------
__global__ __launch_bounds__(256) void detect_kernel(const ushort* __restrict__ x,
                                                     const unsigned char* __restrict__ m,
                                                     int* __restrict__ flags) {
    __shared__ int cnt, weirdAny, weird40, nzNon4;
    if (threadIdx.x == 0) { cnt = 0; weirdAny = 0; weird40 = 0; nzNon4 = 0; }
    __syncthreads();
    for (int t = threadIdx.x; t < 512; t += 256) {
        unsigned u = x[2 * t];
        int e = (int)((u >> 7) & 0xFF);
        if (e >= 100 && e <= 130) atomicAdd(&cnt, 1);
    }
    for (int i = threadIdx.x; i < 4096; i += 256) {
        unsigned b = m[i];
        if (b > 1) { atomicOr(&weirdAny, 1); if ((i & 3) == 0) atomicOr(&weird40, 1); }
        if (b != 0 && (i & 3) != 0) atomicOr(&nzNon4, 1);
    }
    __syncthreads();
    if (threadIdx.x == 0) {
        flags[0] = (cnt < 256) ? 1 : 0;
        flags[1] = weirdAny ? (weird40 ? 2 : 3) : (nzNon4 ? 1 : 0);
    }
}

// -------- unified prep: weight conversions + mask; x read raw everywhere --------
__global__ __launch_bounds__(256) void prep_kernel(
    const void* __restrict__ xs, const void* __restrict__ ms,
    const void* __restrict__ ln1g, const void* __restrict__ ln1b,
    const void* __restrict__ qkvw, const void* __restrict__ qb,
    const void* __restrict__ vb, const void* __restrict__ pw,
    const void* __restrict__ pb, const void* __restrict__ ln2g,
    const void* __restrict__ ln2b, const void* __restrict__ f1w,
    const void* __restrict__ f1b, const void* __restrict__ f2w,
    const void* __restrict__ f2b,
    char* __restrict__ w, const int* __restrict__ flags) {
    bool f32w = flags[0] != 0;
    const size_t MB = 1024 * 1024;
    int bid = blockIdx.x, tid = threadIdx.x;
    if (bid < 2048) return;
    if (!f32w && bid < 8192) return;
    char* small = w + 88 * MB;
    auto cvt8 = [&](const void* src, ushort* dst, int i) {
        if (f32w) {
            const float* s = (const float*)src + i;
            short8 o;
            for (int j = 0; j < 8; j++) o[j] = f2bf(s[j]);
            *(short8*)&dst[i] = o;
        } else {
            *(short8*)&dst[i] = *(const short8*)((const ushort*)src + i);
        }
    };
    if (bid < 3584)       cvt8(qkvw, (ushort*)(w + 64 * MB), ((bid - 2048) * 256 + tid) * 8);
    else if (bid < 4096)  cvt8(pw,   (ushort*)(w + 70 * MB), ((bid - 3584) * 256 + tid) * 8);
    else if (bid < 6144)  cvt8(f1w,  (ushort*)(w + 72 * MB), ((bid - 4096) * 256 + tid) * 8);
    else if (bid < 8192)  cvt8(f2w,  (ushort*)(w + 80 * MB), ((bid - 6144) * 256 + tid) * 8);
    else if (bid < 8198) {
        int e = (bid - 8192) * 2048 + tid * 8;
        const void* src; ushort* dst; int off;
        if (e < 7168) {
            int t = e >> 10; off = e & 1023;
            const void* s0;
            if (t == 0) s0 = ln1g; else if (t == 1) s0 = ln1b; else if (t == 2) s0 = qb;
            else if (t == 3) s0 = vb; else if (t == 4) s0 = pb; else if (t == 5) s0 = ln2g;
            else s0 = ln2b;
            src = s0; dst = (ushort*)(small + t * 4096);
        } else if (e < 8192) { src = f2b; off = e - 7168; dst = (ushort*)(small + 9 * 4096); }
        else                 { src = f1b; off = e - 8192; dst = (ushort*)(small + 7 * 4096); }
        cvt8(src, dst, off);
    } else {
        int enc = flags[1];
        unsigned char* md = (unsigned char*)(small + 10 * 4096);
        int i0 = (bid - 8198) * 2048 + tid * 8;
        for (int j = 0; j < 8; j++) {
            int i = i0 + j;
            unsigned char v;
            if (enc == 0)      v = (((const int*)ms)[i] != 0);
            else if (enc == 1) v = (((const unsigned char*)ms)[i] != 0);
            else if (enc == 2) v = (((const ushort*)ms)[i] != 0);
            else               v = ((((const unsigned*)ms)[i] << 1) != 0);
            md[i] = v;
        }
    }
}

// ---------------- LayerNorm: one wave per row, 4 rows per block -----------------
__global__ __launch_bounds__(256) void ln_kernel(const void* __restrict__ xraw,
                                                 const ushort* __restrict__ g,
                                                 const ushort* __restrict__ b,
                                                 ushort* __restrict__ y,
                                                 const int* __restrict__ flags,
                                                 int rawsel) {
    bool f32in = rawsel && (flags[0] != 0);
    int wave = threadIdx.x >> 6, lane = threadIdx.x & 63;
    int row = blockIdx.x * 4 + wave;
    float f[16];
    if (f32in) {
        const float* xf = (const float*)xraw + (size_t)row * 1024 + lane * 16;
        f32x4 a0 = *(const f32x4*)&xf[0];
        f32x4 a1 = *(const f32x4*)&xf[4];
        f32x4 a2 = *(const f32x4*)&xf[8];
        f32x4 a3 = *(const f32x4*)&xf[12];
        for (int j = 0; j < 4; j++) { f[j] = a0[j]; f[4 + j] = a1[j]; f[8 + j] = a2[j]; f[12 + j] = a3[j]; }
    } else {
        const ushort* xp = (const ushort*)xraw + (size_t)row * 1024 + lane * 16;
        short8 v0 = *(const short8*)xp;
        short8 v1 = *(const short8*)(xp + 8);
        for (int i = 0; i < 8; i++) { f[i] = bf2f(v0[i]); f[i + 8] = bf2f(v1[i]); }
    }
    float s = 0.f, ss = 0.f;
    for (int i = 0; i < 16; i++) { s += f[i]; ss += f[i] * f[i]; }
    for (int o = 1; o < 64; o <<= 1) { s += __shfl_xor(s, o, 64); ss += __shfl_xor(ss, o, 64); }
    float mu = s * (1.f / 1024.f);
    float var = ss * (1.f / 1024.f) - mu * mu;
    float rstd = rsqrtf(var + 1e-5f);
    short8 g0 = *(const short8*)&g[lane * 16];
    short8 g1 = *(const short8*)&g[lane * 16 + 8];
    short8 b0 = *(const short8*)&b[lane * 16];
    short8 b1 = *(const short8*)&b[lane * 16 + 8];
    short8 o0v, o1v;
    for (int i = 0; i < 8; i++) {
        o0v[i] = f2bf((f[i] - mu) * rstd * bf2f(g0[i]) + bf2f(b0[i]));
        o1v[i] = f2bf((f[i + 8] - mu) * rstd * bf2f(g1[i]) + bf2f(b1[i]));
    }
    ushort* yp = y + (size_t)row * 1024 + lane * 16;
    *(short8*)yp = o0v;
    *(short8*)(yp + 8) = o1v;
}

// ---------------- GEMM 128x128x32 + non-temporal epilogue stores ----------------
template <int EPI>
__device__ __forceinline__ void gemm_body(ushort* SM,
                                          const ushort* __restrict__ A,
                                          const void* __restrict__ Wraw,
                                          const ushort* __restrict__ Wconv,
                                          int K,
                                          const ushort* __restrict__ p0,
                                          const void* __restrict__ p1raw,
                                          const ushort* __restrict__ p1conv,
                                          void* __restrict__ o0,
                                          ushort* __restrict__ o1,
                                          const int* __restrict__ flags) {
    bool f32w = flags[0] != 0;
    const ushort* W = f32w ? Wconv : (const ushort*)Wraw;
    int tid = threadIdx.x;
    int wave = tid >> 6, lane = tid & 63;
    int wr = wave >> 1, wc = wave & 1;
    int lr = lane & 15, lg = lane >> 4;
    int m0 = blockIdx.x * 128, n0 = blockIdx.y * 128;
    f32x4 acc[4][4];
    for (int i = 0; i < 4; i++) for (int j = 0; j < 4; j++) acc[i][j] = (f32x4){0.f, 0.f, 0.f, 0.f};

    int s0 = wave * 2;
    int srow = lane >> 2;
    int sslot = (lane & 3) ^ ((srow >> 1) & 3);
    const ushort* gA0 = &A[(size_t)(m0 + s0 * 16 + srow) * K + sslot * 8];
    const ushort* gA1 = gA0 + (size_t)16 * K;
    const ushort* gW0 = &W[(size_t)(n0 + s0 * 16 + srow) * K + sslot * 8];
    const ushort* gW1 = gW0 + (size_t)16 * K;

    auto STAGE = [&](int buf, int k0) {
        ushort* lA = &SM[buf * 4096 + s0 * 512];
        ushort* lW = &SM[12288 + buf * 4096 + s0 * 512];
        GLD_LDS16(gA0 + k0, lA);
        GLD_LDS16(gA1 + k0, lA + 512);
        GLD_LDS16(gW0 + k0, lW);
        GLD_LDS16(gW1 + k0, lW + 512);
    };

    int nk = K >> 5;
    STAGE(0, 0);
    if (nk > 1) {
        STAGE(1, 32);
        asm volatile("s_waitcnt vmcnt(4)" ::: "memory");
    } else {
        asm volatile("s_waitcnt vmcnt(0)" ::: "memory");
    }
    BARRIER_PIN;

    int rs = lg ^ ((lr >> 1) & 3);
    int cur = 0, stg = 2;
    for (int t = 0; t < nk; ++t) {
        if (t + 2 < nk) STAGE(stg, (t + 2) << 5);
        const ushort* Ab = &SM[cur * 4096];
        const ushort* Wb = &SM[12288 + cur * 4096];
        short8 af[4], wf[4];
        for (int mi = 0; mi < 4; mi++) af[mi] = *(const short8*)&Ab[(wr * 64 + mi * 16 + lr) * 32 + rs * 8];
        for (int ni = 0; ni < 4; ni++) wf[ni] = *(const short8*)&Wb[(wc * 64 + ni * 16 + lr) * 32 + rs * 8];
        for (int mi = 0; mi < 4; mi++)
            for (int ni = 0; ni < 4; ni++)
                acc[mi][ni] = __builtin_amdgcn_mfma_f32_16x16x32_bf16(af[mi], wf[ni], acc[mi][ni], 0, 0, 0);
        if (t + 1 < nk) {
            if (t + 2 < nk) asm volatile("s_waitcnt vmcnt(4)" ::: "memory");
            else            asm volatile("s_waitcnt vmcnt(0)" ::: "memory");
            BARRIER_PIN;
        }
        cur = (cur == 2) ? 0 : cur + 1;
        stg = (stg == 2) ? 0 : stg + 1;
    }

    float* Cs = (float*)SM;
    bool of32 = (EPI == 2 || EPI == 3) ? f32w : false;
    int r2 = tid >> 3;
    int lc = tid & 7;
    for (int mi = 0; mi < 4; mi++) {
        __syncthreads();
        int rb = wr * 16 + lg * 4;
        for (int ni = 0; ni < 4; ni++) {
            f32x4 v = acc[mi][ni];
            int cl = wc * 64 + ni * 16 + lr;
            for (int rr = 0; rr < 4; rr++) Cs[(rb + rr) * 132 + cl] = v[rr];
        }
        __syncthreads();
        int grow = m0 + mi * 16 + (r2 < 16 ? r2 : 48 + r2);
        if (EPI == 3 && of32) {
            const ushort* p1 = p1conv;  // x1, always bf16
            for (int k = 0; k < 4; k++) {
                int c0l = k * 32 + lc * 4;
                int gcol = n0 + c0l;
                f32x4 v;
                for (int j = 0; j < 4; j++)
                    v[j] = Cs[r2 * 132 + c0l + j] + bf2f(p0[gcol + j])
                         + bf2f(p1[(size_t)grow * 1024 + gcol + j]);
                ntstore(v, (f32x4*)&((float*)o0)[16777216 + (size_t)grow * 1024 + gcol]);
            }
        } else {
            for (int half = 0; half < 2; half++) {
                int c0l = half * 64 + lc * 8;
                int gcol = n0 + c0l;
                float hv[8];
                for (int j = 0; j < 8; j++) hv[j] = Cs[r2 * 132 + c0l + j];
                short8 o;
                if (EPI == 0) {
                    int part = gcol >> 10, cc = gcol & 1023;
                    if (part == 0)
                        for (int j = 0; j < 8; j++) o[j] = f2bf((hv[j] + bf2f(p0[cc + j])) * 0.18033688f);
                    else if (part == 1)
                        for (int j = 0; j < 8; j++) o[j] = f2bf(hv[j]);
                    else
                        for (int j = 0; j < 8; j++) o[j] = f2bf(hv[j] + bf2f(p1conv[cc + j]));
                    ntstore(o, (short8*)&((ushort*)o0)[(size_t)grow * 3072 + gcol]);
                } else if (EPI == 1) {
                    if (f32w) {
                        const float* p1f = (const float*)p1raw;
                        for (int j = 0; j < 8; j++)
                            o[j] = f2bf(hv[j] + bf2f(p0[gcol + j])
                                      + p1f[(size_t)grow * 1024 + gcol + j]);
                    } else {
                        const ushort* p1b = (const ushort*)p1raw;
                        for (int j = 0; j < 8; j++)
                            o[j] = f2bf(hv[j] + bf2f(p0[gcol + j])
                                      + bf2f(p1b[(size_t)grow * 1024 + gcol + j]));
                    }
                    *(short8*)&((ushort*)o0)[(size_t)grow * 1024 + gcol] = o;
                } else if (EPI == 2) {
                    float h[8];
                    short8 og;
                    for (int j = 0; j < 8; j++) {
                        h[j] = hv[j] + bf2f(p0[gcol + j]);
                        og[j] = f2bf(gelu_fast(h[j]));
                    }
                    ntstore(og, (short8*)&o1[(size_t)grow * 4096 + gcol]);
                    if (of32) {
                        float* dst = &((float*)o0)[(size_t)grow * 4096 + gcol];
                        f32x4 v0 = (f32x4){h[0], h[1], h[2], h[3]};
                        f32x4 v1 = (f32x4){h[4], h[5], h[6], h[7]};
                        ntstore(v0, (f32x4*)&dst[0]);
                        ntstore(v1, (f32x4*)&dst[4]);
                    } else {
                        short8 oh;
                        for (int j = 0; j < 8; j++) oh[j] = f2bf(h[j]);
                        ntstore(oh, (short8*)&((ushort*)o0)[(size_t)grow * 4096 + gcol]);
                    }
                } else {
                    const ushort* p1 = p1conv;  // x1, always bf16
                    for (int j = 0; j < 8; j++)
                        o[j] = f2bf(hv[j] + bf2f(p0[gcol + j])
                                  + bf2f(p1[(size_t)grow * 1024 + gcol + j]));
                    ntstore(o, (short8*)&((ushort*)o0)[16777216 + (size_t)grow * 1024 + gcol]);
                }
            }
        }
    }
}

#define GEMM_WRAP(NAME, EPI)                                                          \
__global__ __launch_bounds__(256) void NAME(const ushort* __restrict__ A,            \
                                            const void* __restrict__ Wraw,           \
                                            const ushort* __restrict__ Wconv, int K, \
                                            const ushort* __restrict__ p0,           \
                                            const void* __restrict__ p1raw,          \
                                            const ushort* __restrict__ p1conv,       \
                                            void* __restrict__ o0,                   \
                                            ushort* __restrict__ o1,                 \
                                            const int* __restrict__ flags) {         \
    __shared__ ushort SM[24576];                                                     \
    gemm_body<EPI>(SM, A, Wraw, Wconv, K, p0, p1raw, p1conv, o0, o1, flags);         \
}

GEMM_WRAP(gemm_qkv, 0)
GEMM_WRAP(gemm_proj, 1)
GEMM_WRAP(gemm_fc1, 2)
GEMM_WRAP(gemm_fc2, 3)

// ---------------- V transpose: qkv v-part [B,N,H,64] -> vT [B,H,64,N] ----------------
__global__ __launch_bounds__(256) void vtrans_kernel(const ushort* __restrict__ qkv,
                                                     ushort* __restrict__ vT) {
    __shared__ ushort T[64][72];
    int bh = blockIdx.x;
    int b = bh >> 4, h = bh & 15;
    int n0 = blockIdx.y * 64;
    int t = threadIdx.x;
    int r = t >> 2;
    int c0 = (t & 3) * 16;
    const ushort* src = qkv + (size_t)(b * 2048 + n0 + r) * 3072 + 2048 + h * 64 + c0;
    *(short8*)&T[r][c0]     = *(const short8*)&src[0];
    *(short8*)&T[r][c0 + 8] = *(const short8*)&src[8];
    __syncthreads();
    int d = t >> 2;
    int g0 = (t & 3) * 16;
    short8 o0v, o1v;
    for (int j = 0; j < 8; j++) { o0v[j] = T[g0 + j][d]; o1v[j] = T[g0 + 8 + j][d]; }
    ushort* dst = vT + ((size_t)bh * 64 + d) * 2048 + n0 + g0;
    *(short8*)&dst[0] = o0v;
    *(short8*)&dst[8] = o1v;
}

// ---------------- Flash attention (round-16 config): QBLK=32/wave + setprio --------
__global__ __launch_bounds__(256) void attn_kernel(const ushort* __restrict__ qkv,
                                                   const ushort* __restrict__ vT,
                                                   const unsigned char* __restrict__ mask,
                                                   ushort* __restrict__ ao) {
    __shared__ ushort Ks[2][4096];
    __shared__ ushort Vs[2][4096];
    __shared__ unsigned Plw[4][544];
    __shared__ unsigned Pmf[1024];

    int tid = threadIdx.x, wave = tid >> 6, lane = tid & 63;
    int bid = (blockIdx.x & 7) * 64 + (blockIdx.x >> 3);  // XCD swizzle (512%8==0)
    int g = bid * 4 + wave;
    int b = g >> 10;
    int h = (g >> 6) & 15;
    int qt = g & 63;
    int lr = lane & 15, lg = lane >> 4;

    const ushort* qp = qkv + (size_t)(b * 2048 + qt * 32) * 3072 + h * 64;
    const ushort* kp = qkv + (size_t)(b * 2048) * 3072 + 1024 + h * 64;
    const ushort* vp = vT + ((size_t)(b * 16 + h) * 64) * 2048;
    const unsigned char* mk = mask + b * 2048;

    for (int i = tid; i < 1024; i += 256) {
        unsigned lo = mk[2 * i] ? 0u : 0xFFFFu;
        unsigned hi = mk[2 * i + 1] ? 0u : 0xFFFF0000u;
        Pmf[i] = lo | hi;
    }

    short8 qa[2][2];
    for (int sub = 0; sub < 2; sub++)
        for (int ks = 0; ks < 2; ks++)
            qa[sub][ks] = *(const short8*)&qp[(sub * 16 + lr) * 3072 + ks * 32 + lg * 8];
    short8 ones;
    for (int j = 0; j < 8; j++) ones[j] = (short)0x3F80;

    int srowoff = lane >> 3;
    int sslot = (lane & 7) ^ srowoff;
    int rs0 = lg ^ (lr & 7);
    int rs1 = (4 + lg) ^ (lr & 7);

    f32x4 accT[2][4];
    f32x4 accL[2];
    for (int s = 0; s < 2; s++) {
        accL[s] = (f32x4){0.f, 0.f, 0.f, 0.f};
        for (int i = 0; i < 4; i++) accT[s][i] = (f32x4){0.f, 0.f, 0.f, 0.f};
    }

    auto STAGEKV = [&](int buf, int c0) {
        const ushort* ksrc = kp + (size_t)(c0 + wave * 16 + srowoff) * 3072 + sslot * 8;
        GLD_LDS16(ksrc, &Ks[buf][wave * 1024]);
        GLD_LDS16(ksrc + (size_t)8 * 3072, &Ks[buf][wave * 1024 + 512]);
        const ushort* vsrc = vp + (size_t)(wave * 16 + srowoff) * 2048 + c0 + sslot * 8;
        GLD_LDS16(vsrc, &Vs[buf][wave * 1024]);
        GLD_LDS16(vsrc + (size_t)8 * 2048, &Vs[buf][wave * 1024 + 512]);
    };

    STAGEKV(0, 0);
    __syncthreads();

    for (int it = 0; it < 32; ++it) {
        int c0 = it * 64;
        int cur = it & 1;
        if (it < 31) STAGEKV(cur ^ 1, c0 + 64);

        unsigned mw[4][2];
        for (int t = 0; t < 4; t++) {
            uint2 m2 = *(const uint2*)&Pmf[it * 32 + 8 * t + 2 * lg];
            mw[t][0] = m2.x; mw[t][1] = m2.y;
        }
        f32x4 st[2][4];
        __builtin_amdgcn_s_setprio(1);
        for (int t = 0; t < 4; t++) {
            int row = t * 16 + lr;
            short8 kf0 = *(const short8*)&Ks[cur][row * 64 + rs0 * 8];
            short8 kf1 = *(const short8*)&Ks[cur][row * 64 + rs1 * 8];
            for (int sub = 0; sub < 2; sub++) {
                f32x4 z = (f32x4){0.f, 0.f, 0.f, 0.f};
                z = __builtin_amdgcn_mfma_f32_16x16x32_bf16(kf0, qa[sub][0], z, 0, 0, 0);
                z = __builtin_amdgcn_mfma_f32_16x16x32_bf16(kf1, qa[sub][1], z, 0, 0, 0);
                st[sub][t] = z;
            }
        }
        __builtin_amdgcn_s_setprio(0);
        short8 vf[2][4];
        for (int ks = 0; ks < 2; ks++) {
            int rsk = ks ? rs1 : rs0;
            for (int nt = 0; nt < 4; nt++)
                vf[ks][nt] = *(const short8*)&Vs[cur][(nt * 16 + lr) * 64 + rsk * 8];
        }
        for (int sub = 0; sub < 2; sub++) {
            for (int t = 0; t < 4; t++) {
                for (int rrh = 0; rrh < 2; rrh++) {
                    float plo = ex2(st[sub][t][2 * rrh]);
                    float phi = ex2(st[sub][t][2 * rrh + 1]);
                    unsigned w = cvtpk(plo, phi) & mw[t][rrh];
                    Plw[wave][(8 * t + 2 * lg + rrh) * 17 + lr] = w;
                }
            }
            __builtin_amdgcn_s_setprio(1);
            for (int ks = 0; ks < 2; ks++) {
                unsigned wu[4];
                for (int jj = 0; jj < 4; jj++)
                    wu[jj] = Plw[wave][(16 * ks + 4 * lg + jj) * 17 + lr];
                short8 pf;
                __builtin_memcpy(&pf, wu, 16);
                accL[sub] = __builtin_amdgcn_mfma_f32_16x16x32_bf16(ones, pf, accL[sub], 0, 0, 0);
                for (int nt = 0; nt < 4; nt++)
                    accT[sub][nt] = __builtin_amdgcn_mfma_f32_16x16x32_bf16(vf[ks][nt], pf, accT[sub][nt], 0, 0, 0);
            }
            __builtin_amdgcn_s_setprio(0);
        }
        __syncthreads();
    }

    for (int sub = 0; sub < 2; sub++) {
        float ls = accL[sub][0];
        float inv = (ls > 0.f) ? 1.f / ls : 0.f;
        ushort* op = ao + ((size_t)(b * 2048 + qt * 32 + sub * 16) * 1024) + h * 64;
        for (int nt = 0; nt < 4; nt++) {
            unsigned w0 = cvtpk(accT[sub][nt][0] * inv, accT[sub][nt][1] * inv);
            unsigned w1 = cvtpk(accT[sub][nt][2] * inv, accT[sub][nt][3] * inv);
            uint2 ov; ov.x = w0; ov.y = w1;
            *(uint2*)&op[lr * 1024 + 16 * nt + 4 * lg] = ov;
        }
    }
}

extern "C" void kernel_launch(void* const* d_in, const int* in_sizes, int n_in,
                              void* d_out, int out_size, void* d_ws, size_t ws_size,
                              hipStream_t stream) {
    (void)in_sizes; (void)n_in; (void)out_size; (void)ws_size;

    char* w = (char*)d_ws;
    const size_t MB = 1024 * 1024;
    ushort* xn  = (ushort*)(w + 0 * MB);
    ushort* qkv = (ushort*)(w + 8 * MB);
    ushort* vT  = (ushort*)(w + 32 * MB);
    ushort* x1  = (ushort*)(w + 40 * MB);
    ushort* x2n = (ushort*)(w + 48 * MB);
    ushort* gh  = (ushort*)(w + 8 * MB);    // overlays qkv+vT (dead post-attn)
    ushort* qkvw_c = (ushort*)(w + 64 * MB);
    ushort* projw_c= (ushort*)(w + 70 * MB);
    ushort* fc1w_c = (ushort*)(w + 72 * MB);
    ushort* fc2w_c = (ushort*)(w + 80 * MB);
    char* small = w + 88 * MB;
    ushort* ln1g_c = (ushort*)(small + 0 * 4096);
    ushort* ln1b_c = (ushort*)(small + 1 * 4096);
    ushort* qbias_c= (ushort*)(small + 2 * 4096);
    ushort* vbias_c= (ushort*)(small + 3 * 4096);
    ushort* projb_c= (ushort*)(small + 4 * 4096);
    ushort* ln2g_c = (ushort*)(small + 5 * 4096);
    ushort* ln2b_c = (ushort*)(small + 6 * 4096);
    ushort* fc1b_c = (ushort*)(small + 7 * 4096);
    ushort* fc2b_c = (ushort*)(small + 9 * 4096);
    unsigned char* mask_c = (unsigned char*)(small + 10 * 4096);
    int* flags = (int*)(small + 11 * 4096);
    ushort* ao = xn;

    detect_kernel<<<1, 256, 0, stream>>>((const ushort*)d_in[0],
                                         (const unsigned char*)d_in[1], flags);
    prep_kernel<<<8200, 256, 0, stream>>>(d_in[0], d_in[1], d_in[2], d_in[3], d_in[4],
                                          d_in[5], d_in[6], d_in[7], d_in[8], d_in[9],
                                          d_in[10], d_in[11], d_in[12], d_in[13], d_in[14],
                                          w, flags);

    ln_kernel<<<1024, 256, 0, stream>>>(d_in[0], ln1g_c, ln1b_c, xn, flags, 1);
    gemm_qkv<<<dim3(32, 24), 256, 0, stream>>>(xn, d_in[4], qkvw_c, 1024, qbias_c,
                                               vbias_c, vbias_c, qkv, nullptr, flags);
    vtrans_kernel<<<dim3(32, 32), 256, 0, stream>>>(qkv, vT);
    attn_kernel<<<512, 256, 0, stream>>>(qkv, vT, mask_c, ao);
    gemm_proj<<<dim3(32, 8), 256, 0, stream>>>(ao, d_in[7], projw_c, 1024, projb_c,
                                               d_in[0], nullptr, x1, nullptr, flags);
    ln_kernel<<<1024, 256, 0, stream>>>(x1, ln2g_c, ln2b_c, x2n, flags, 0);
    gemm_fc1<<<dim3(32, 32), 256, 0, stream>>>(x2n, d_in[11], fc1w_c, 1024, fc1b_c,
                                               fc1b_c, fc1b_c, d_out, gh, flags);
    gemm_fc2<<<dim3(32, 8), 256, 0, stream>>>(gh, d_in[13], fc2w_c, 4096, fc2b_c,
                                              x1, x1, d_out, nullptr, flags);
}

// Round 18
// 251.540 us; speedup vs baseline: 1.0398x; 1.0398x over previous
//
#include <hip/hip_runtime.h>
#include <hip/hip_bf16.h>

typedef __attribute__((ext_vector_type(8))) short short8;
typedef __attribute__((ext_vector_type(4))) short short4v;
typedef __attribute__((ext_vector_type(4))) float f32x4;

__device__ inline float bf2f(short s) {
    unsigned u = ((unsigned)(unsigned short)s) << 16;
    float f; __builtin_memcpy(&f, &u, 4); return f;
}
__device__ inline short f2bf(float f) {
    unsigned u; __builtin_memcpy(&u, &f, 4);
    unsigned r = (u + 0x7fffu + ((u >> 16) & 1u)) >> 16;
    return (short)r;
}
__device__ inline float ex2(float x) {
    float r; asm("v_exp_f32 %0, %1" : "=v"(r) : "v"(x)); return r;
}
__device__ inline unsigned cvtpk(float lo, float hi) {
    unsigned r; asm("v_cvt_pk_bf16_f32 %0, %1, %2" : "=v"(r) : "v"(lo), "v"(hi)); return r;
}
__device__ inline float gelu_fast(float x) {
    float xx = x * x;
    float u2 = x * fmaf(0.10294323f, xx, 2.3022085f);
    float t = ex2(u2);
    return x - x * __builtin_amdgcn_rcpf(t + 1.f);
}

#define GLD_LDS16(g, l) __builtin_amdgcn_global_load_lds( \
    (const __attribute__((address_space(1))) void*)(g),   \
    (__attribute__((address_space(3))) void*)(l), 16, 0, 0)

#define BARRIER_PIN do { __builtin_amdgcn_s_barrier(); __builtin_amdgcn_sched_barrier(0); } while (0)

// -------- detect input dtype world + mask encoding (1 block) --------
__global__ __launch_bounds__(256) void detect_kernel(const ushort* __restrict__ x,
                                                     const unsigned char* __restrict__ m,
                                                     int* __restrict__ flags) {
    __shared__ int cnt, weirdAny, weird40, nzNon4;
    if (threadIdx.x == 0) { cnt = 0; weirdAny = 0; weird40 = 0; nzNon4 = 0; }
    __syncthreads();
    for (int t = threadIdx.x; t < 512; t += 256) {
        unsigned u = x[2 * t];
        int e = (int)((u >> 7) & 0xFF);
        if (e >= 100 && e <= 130) atomicAdd(&cnt, 1);
    }
    for (int i = threadIdx.x; i < 4096; i += 256) {
        unsigned b = m[i];
        if (b > 1) { atomicOr(&weirdAny, 1); if ((i & 3) == 0) atomicOr(&weird40, 1); }
        if (b != 0 && (i & 3) != 0) atomicOr(&nzNon4, 1);
    }
    __syncthreads();
    if (threadIdx.x == 0) {
        flags[0] = (cnt < 256) ? 1 : 0;
        flags[1] = weirdAny ? (weird40 ? 2 : 3) : (nzNon4 ? 1 : 0);
    }
}

// -------- unified prep: weight conversions + mask; x read raw everywhere --------
__global__ __launch_bounds__(256) void prep_kernel(
    const void* __restrict__ xs, const void* __restrict__ ms,
    const void* __restrict__ ln1g, const void* __restrict__ ln1b,
    const void* __restrict__ qkvw, const void* __restrict__ qb,
    const void* __restrict__ vb, const void* __restrict__ pw,
    const void* __restrict__ pb, const void* __restrict__ ln2g,
    const void* __restrict__ ln2b, const void* __restrict__ f1w,
    const void* __restrict__ f1b, const void* __restrict__ f2w,
    const void* __restrict__ f2b,
    char* __restrict__ w, const int* __restrict__ flags) {
    bool f32w = flags[0] != 0;
    const size_t MB = 1024 * 1024;
    int bid = blockIdx.x, tid = threadIdx.x;
    if (bid < 2048) return;
    if (!f32w && bid < 8192) return;
    char* small = w + 88 * MB;
    auto cvt8 = [&](const void* src, ushort* dst, int i) {
        if (f32w) {
            const float* s = (const float*)src + i;
            short8 o;
            for (int j = 0; j < 8; j++) o[j] = f2bf(s[j]);
            *(short8*)&dst[i] = o;
        } else {
            *(short8*)&dst[i] = *(const short8*)((const ushort*)src + i);
        }
    };
    if (bid < 3584)       cvt8(qkvw, (ushort*)(w + 64 * MB), ((bid - 2048) * 256 + tid) * 8);
    else if (bid < 4096)  cvt8(pw,   (ushort*)(w + 70 * MB), ((bid - 3584) * 256 + tid) * 8);
    else if (bid < 6144)  cvt8(f1w,  (ushort*)(w + 72 * MB), ((bid - 4096) * 256 + tid) * 8);
    else if (bid < 8192)  cvt8(f2w,  (ushort*)(w + 80 * MB), ((bid - 6144) * 256 + tid) * 8);
    else if (bid < 8198) {
        int e = (bid - 8192) * 2048 + tid * 8;
        const void* src; ushort* dst; int off;
        if (e < 7168) {
            int t = e >> 10; off = e & 1023;
            const void* s0;
            if (t == 0) s0 = ln1g; else if (t == 1) s0 = ln1b; else if (t == 2) s0 = qb;
            else if (t == 3) s0 = vb; else if (t == 4) s0 = pb; else if (t == 5) s0 = ln2g;
            else s0 = ln2b;
            src = s0; dst = (ushort*)(small + t * 4096);
        } else if (e < 8192) { src = f2b; off = e - 7168; dst = (ushort*)(small + 9 * 4096); }
        else                 { src = f1b; off = e - 8192; dst = (ushort*)(small + 7 * 4096); }
        cvt8(src, dst, off);
    } else {
        int enc = flags[1];
        unsigned char* md = (unsigned char*)(small + 10 * 4096);
        int i0 = (bid - 8198) * 2048 + tid * 8;
        for (int j = 0; j < 8; j++) {
            int i = i0 + j;
            unsigned char v;
            if (enc == 0)      v = (((const int*)ms)[i] != 0);
            else if (enc == 1) v = (((const unsigned char*)ms)[i] != 0);
            else if (enc == 2) v = (((const ushort*)ms)[i] != 0);
            else               v = ((((const unsigned*)ms)[i] << 1) != 0);
            md[i] = v;
        }
    }
}

// ---------------- LayerNorm: one wave per row, 4 rows per block -----------------
__global__ __launch_bounds__(256) void ln_kernel(const void* __restrict__ xraw,
                                                 const ushort* __restrict__ g,
                                                 const ushort* __restrict__ b,
                                                 ushort* __restrict__ y,
                                                 const int* __restrict__ flags,
                                                 int rawsel) {
    bool f32in = rawsel && (flags[0] != 0);
    int wave = threadIdx.x >> 6, lane = threadIdx.x & 63;
    int row = blockIdx.x * 4 + wave;
    float f[16];
    if (f32in) {
        const float* xf = (const float*)xraw + (size_t)row * 1024 + lane * 16;
        f32x4 a0 = *(const f32x4*)&xf[0];
        f32x4 a1 = *(const f32x4*)&xf[4];
        f32x4 a2 = *(const f32x4*)&xf[8];
        f32x4 a3 = *(const f32x4*)&xf[12];
        for (int j = 0; j < 4; j++) { f[j] = a0[j]; f[4 + j] = a1[j]; f[8 + j] = a2[j]; f[12 + j] = a3[j]; }
    } else {
        const ushort* xp = (const ushort*)xraw + (size_t)row * 1024 + lane * 16;
        short8 v0 = *(const short8*)xp;
        short8 v1 = *(const short8*)(xp + 8);
        for (int i = 0; i < 8; i++) { f[i] = bf2f(v0[i]); f[i + 8] = bf2f(v1[i]); }
    }
    float s = 0.f, ss = 0.f;
    for (int i = 0; i < 16; i++) { s += f[i]; ss += f[i] * f[i]; }
    for (int o = 1; o < 64; o <<= 1) { s += __shfl_xor(s, o, 64); ss += __shfl_xor(ss, o, 64); }
    float mu = s * (1.f / 1024.f);
    float var = ss * (1.f / 1024.f) - mu * mu;
    float rstd = rsqrtf(var + 1e-5f);
    short8 g0 = *(const short8*)&g[lane * 16];
    short8 g1 = *(const short8*)&g[lane * 16 + 8];
    short8 b0 = *(const short8*)&b[lane * 16];
    short8 b1 = *(const short8*)&b[lane * 16 + 8];
    short8 o0v, o1v;
    for (int i = 0; i < 8; i++) {
        o0v[i] = f2bf((f[i] - mu) * rstd * bf2f(g0[i]) + bf2f(b0[i]));
        o1v[i] = f2bf((f[i + 8] - mu) * rstd * bf2f(g1[i]) + bf2f(b1[i]));
    }
    ushort* yp = y + (size_t)row * 1024 + lane * 16;
    *(short8*)yp = o0v;
    *(short8*)(yp + 8) = o1v;
}

// ---------------- GEMM 128x128x32 (round-16 verbatim) ----------------
template <int EPI>
__device__ __forceinline__ void gemm_body(ushort* SM,
                                          const ushort* __restrict__ A,
                                          const void* __restrict__ Wraw,
                                          const ushort* __restrict__ Wconv,
                                          int K,
                                          const ushort* __restrict__ p0,
                                          const void* __restrict__ p1raw,
                                          const ushort* __restrict__ p1conv,
                                          void* __restrict__ o0,
                                          ushort* __restrict__ o1,
                                          const int* __restrict__ flags) {
    bool f32w = flags[0] != 0;
    const ushort* W = f32w ? Wconv : (const ushort*)Wraw;
    int tid = threadIdx.x;
    int wave = tid >> 6, lane = tid & 63;
    int wr = wave >> 1, wc = wave & 1;
    int lr = lane & 15, lg = lane >> 4;
    int m0 = blockIdx.x * 128, n0 = blockIdx.y * 128;
    f32x4 acc[4][4];
    for (int i = 0; i < 4; i++) for (int j = 0; j < 4; j++) acc[i][j] = (f32x4){0.f, 0.f, 0.f, 0.f};

    int s0 = wave * 2;
    int srow = lane >> 2;
    int sslot = (lane & 3) ^ ((srow >> 1) & 3);
    const ushort* gA0 = &A[(size_t)(m0 + s0 * 16 + srow) * K + sslot * 8];
    const ushort* gA1 = gA0 + (size_t)16 * K;
    const ushort* gW0 = &W[(size_t)(n0 + s0 * 16 + srow) * K + sslot * 8];
    const ushort* gW1 = gW0 + (size_t)16 * K;

    auto STAGE = [&](int buf, int k0) {
        ushort* lA = &SM[buf * 4096 + s0 * 512];
        ushort* lW = &SM[12288 + buf * 4096 + s0 * 512];
        GLD_LDS16(gA0 + k0, lA);
        GLD_LDS16(gA1 + k0, lA + 512);
        GLD_LDS16(gW0 + k0, lW);
        GLD_LDS16(gW1 + k0, lW + 512);
    };

    int nk = K >> 5;
    STAGE(0, 0);
    if (nk > 1) {
        STAGE(1, 32);
        asm volatile("s_waitcnt vmcnt(4)" ::: "memory");
    } else {
        asm volatile("s_waitcnt vmcnt(0)" ::: "memory");
    }
    BARRIER_PIN;

    int rs = lg ^ ((lr >> 1) & 3);
    int cur = 0, stg = 2;
    for (int t = 0; t < nk; ++t) {
        if (t + 2 < nk) STAGE(stg, (t + 2) << 5);
        const ushort* Ab = &SM[cur * 4096];
        const ushort* Wb = &SM[12288 + cur * 4096];
        short8 af[4], wf[4];
        for (int mi = 0; mi < 4; mi++) af[mi] = *(const short8*)&Ab[(wr * 64 + mi * 16 + lr) * 32 + rs * 8];
        for (int ni = 0; ni < 4; ni++) wf[ni] = *(const short8*)&Wb[(wc * 64 + ni * 16 + lr) * 32 + rs * 8];
        for (int mi = 0; mi < 4; mi++)
            for (int ni = 0; ni < 4; ni++)
                acc[mi][ni] = __builtin_amdgcn_mfma_f32_16x16x32_bf16(af[mi], wf[ni], acc[mi][ni], 0, 0, 0);
        if (t + 1 < nk) {
            if (t + 2 < nk) asm volatile("s_waitcnt vmcnt(4)" ::: "memory");
            else            asm volatile("s_waitcnt vmcnt(0)" ::: "memory");
            BARRIER_PIN;
        }
        cur = (cur == 2) ? 0 : cur + 1;
        stg = (stg == 2) ? 0 : stg + 1;
    }

    float* Cs = (float*)SM;
    bool of32 = (EPI == 2 || EPI == 3) ? f32w : false;
    int r2 = tid >> 3;
    int lc = tid & 7;
    for (int mi = 0; mi < 4; mi++) {
        __syncthreads();
        int rb = wr * 16 + lg * 4;
        for (int ni = 0; ni < 4; ni++) {
            f32x4 v = acc[mi][ni];
            int cl = wc * 64 + ni * 16 + lr;
            for (int rr = 0; rr < 4; rr++) Cs[(rb + rr) * 132 + cl] = v[rr];
        }
        __syncthreads();
        int grow = m0 + mi * 16 + (r2 < 16 ? r2 : 48 + r2);
        if (EPI == 3 && of32) {
            const ushort* p1 = p1conv;  // x1, always bf16
            for (int k = 0; k < 4; k++) {
                int c0l = k * 32 + lc * 4;
                int gcol = n0 + c0l;
                f32x4 v;
                for (int j = 0; j < 4; j++)
                    v[j] = Cs[r2 * 132 + c0l + j] + bf2f(p0[gcol + j])
                         + bf2f(p1[(size_t)grow * 1024 + gcol + j]);
                *(f32x4*)&((float*)o0)[16777216 + (size_t)grow * 1024 + gcol] = v;
            }
        } else {
            for (int half = 0; half < 2; half++) {
                int c0l = half * 64 + lc * 8;
                int gcol = n0 + c0l;
                float hv[8];
                for (int j = 0; j < 8; j++) hv[j] = Cs[r2 * 132 + c0l + j];
                short8 o;
                if (EPI == 0) {
                    int part = gcol >> 10, cc = gcol & 1023;
                    if (part == 0)
                        for (int j = 0; j < 8; j++) o[j] = f2bf((hv[j] + bf2f(p0[cc + j])) * 0.18033688f);
                    else if (part == 1)
                        for (int j = 0; j < 8; j++) o[j] = f2bf(hv[j]);
                    else
                        for (int j = 0; j < 8; j++) o[j] = f2bf(hv[j] + bf2f(p1conv[cc + j]));
                    *(short8*)&((ushort*)o0)[(size_t)grow * 3072 + gcol] = o;
                } else if (EPI == 1) {
                    if (f32w) {
                        const float* p1f = (const float*)p1raw;
                        for (int j = 0; j < 8; j++)
                            o[j] = f2bf(hv[j] + bf2f(p0[gcol + j])
                                      + p1f[(size_t)grow * 1024 + gcol + j]);
                    } else {
                        const ushort* p1b = (const ushort*)p1raw;
                        for (int j = 0; j < 8; j++)
                            o[j] = f2bf(hv[j] + bf2f(p0[gcol + j])
                                      + bf2f(p1b[(size_t)grow * 1024 + gcol + j]));
                    }
                    *(short8*)&((ushort*)o0)[(size_t)grow * 1024 + gcol] = o;
                } else if (EPI == 2) {
                    float h[8];
                    short8 og;
                    for (int j = 0; j < 8; j++) {
                        h[j] = hv[j] + bf2f(p0[gcol + j]);
                        og[j] = f2bf(gelu_fast(h[j]));
                    }
                    *(short8*)&o1[(size_t)grow * 4096 + gcol] = og;
                    if (of32) {
                        float* dst = &((float*)o0)[(size_t)grow * 4096 + gcol];
                        *(f32x4*)&dst[0] = (f32x4){h[0], h[1], h[2], h[3]};
                        *(f32x4*)&dst[4] = (f32x4){h[4], h[5], h[6], h[7]};
                    } else {
                        short8 oh;
                        for (int j = 0; j < 8; j++) oh[j] = f2bf(h[j]);
                        *(short8*)&((ushort*)o0)[(size_t)grow * 4096 + gcol] = oh;
                    }
                } else {
                    const ushort* p1 = p1conv;  // x1, always bf16
                    for (int j = 0; j < 8; j++)
                        o[j] = f2bf(hv[j] + bf2f(p0[gcol + j])
                                  + bf2f(p1[(size_t)grow * 1024 + gcol + j]));
                    *(short8*)&((ushort*)o0)[16777216 + (size_t)grow * 1024 + gcol] = o;
                }
            }
        }
    }
}

#define GEMM_WRAP(NAME, EPI)                                                          \
__global__ __launch_bounds__(256) void NAME(const ushort* __restrict__ A,            \
                                            const void* __restrict__ Wraw,           \
                                            const ushort* __restrict__ Wconv, int K, \
                                            const ushort* __restrict__ p0,           \
                                            const void* __restrict__ p1raw,          \
                                            const ushort* __restrict__ p1conv,       \
                                            void* __restrict__ o0,                   \
                                            ushort* __restrict__ o1,                 \
                                            const int* __restrict__ flags) {         \
    __shared__ ushort SM[24576];                                                     \
    gemm_body<EPI>(SM, A, Wraw, Wconv, K, p0, p1raw, p1conv, o0, o1, flags);         \
}

GEMM_WRAP(gemm_qkv, 0)
GEMM_WRAP(gemm_proj, 1)
GEMM_WRAP(gemm_fc1, 2)
GEMM_WRAP(gemm_fc2, 3)

// ---------------- V transpose: qkv v-part [B,N,H,64] -> vT [B,H,64,N] ----------------
__global__ __launch_bounds__(256) void vtrans_kernel(const ushort* __restrict__ qkv,
                                                     ushort* __restrict__ vT) {
    __shared__ ushort T[64][72];
    int bh = blockIdx.x;
    int b = bh >> 4, h = bh & 15;
    int n0 = blockIdx.y * 64;
    int t = threadIdx.x;
    int r = t >> 2;
    int c0 = (t & 3) * 16;
    const ushort* src = qkv + (size_t)(b * 2048 + n0 + r) * 3072 + 2048 + h * 64 + c0;
    *(short8*)&T[r][c0]     = *(const short8*)&src[0];
    *(short8*)&T[r][c0 + 8] = *(const short8*)&src[8];
    __syncthreads();
    int d = t >> 2;
    int g0 = (t & 3) * 16;
    short8 o0v, o1v;
    for (int j = 0; j < 8; j++) { o0v[j] = T[g0 + j][d]; o1v[j] = T[g0 + 8 + j][d]; }
    ushort* dst = vT + ((size_t)bh * 64 + d) * 2048 + n0 + g0;
    *(short8*)&dst[0] = o0v;
    *(short8*)&dst[8] = o1v;
}

// ---------------- Flash attention (round-16 config): QBLK=32/wave + setprio --------
__global__ __launch_bounds__(256) void attn_kernel(const ushort* __restrict__ qkv,
                                                   const ushort* __restrict__ vT,
                                                   const unsigned char* __restrict__ mask,
                                                   ushort* __restrict__ ao) {
    __shared__ ushort Ks[2][4096];
    __shared__ ushort Vs[2][4096];
    __shared__ unsigned Plw[4][544];
    __shared__ unsigned Pmf[1024];

    int tid = threadIdx.x, wave = tid >> 6, lane = tid & 63;
    int bid = (blockIdx.x & 7) * 64 + (blockIdx.x >> 3);  // XCD swizzle (512%8==0)
    int g = bid * 4 + wave;
    int b = g >> 10;
    int h = (g >> 6) & 15;
    int qt = g & 63;
    int lr = lane & 15, lg = lane >> 4;

    const ushort* qp = qkv + (size_t)(b * 2048 + qt * 32) * 3072 + h * 64;
    const ushort* kp = qkv + (size_t)(b * 2048) * 3072 + 1024 + h * 64;
    const ushort* vp = vT + ((size_t)(b * 16 + h) * 64) * 2048;
    const unsigned char* mk = mask + b * 2048;

    for (int i = tid; i < 1024; i += 256) {
        unsigned lo = mk[2 * i] ? 0u : 0xFFFFu;
        unsigned hi = mk[2 * i + 1] ? 0u : 0xFFFF0000u;
        Pmf[i] = lo | hi;
    }

    short8 qa[2][2];
    for (int sub = 0; sub < 2; sub++)
        for (int ks = 0; ks < 2; ks++)
            qa[sub][ks] = *(const short8*)&qp[(sub * 16 + lr) * 3072 + ks * 32 + lg * 8];
    short8 ones;
    for (int j = 0; j < 8; j++) ones[j] = (short)0x3F80;

    int srowoff = lane >> 3;
    int sslot = (lane & 7) ^ srowoff;
    int rs0 = lg ^ (lr & 7);
    int rs1 = (4 + lg) ^ (lr & 7);

    f32x4 accT[2][4];
    f32x4 accL[2];
    for (int s = 0; s < 2; s++) {
        accL[s] = (f32x4){0.f, 0.f, 0.f, 0.f};
        for (int i = 0; i < 4; i++) accT[s][i] = (f32x4){0.f, 0.f, 0.f, 0.f};
    }

    auto STAGEKV = [&](int buf, int c0) {
        const ushort* ksrc = kp + (size_t)(c0 + wave * 16 + srowoff) * 3072 + sslot * 8;
        GLD_LDS16(ksrc, &Ks[buf][wave * 1024]);
        GLD_LDS16(ksrc + (size_t)8 * 3072, &Ks[buf][wave * 1024 + 512]);
        const ushort* vsrc = vp + (size_t)(wave * 16 + srowoff) * 2048 + c0 + sslot * 8;
        GLD_LDS16(vsrc, &Vs[buf][wave * 1024]);
        GLD_LDS16(vsrc + (size_t)8 * 2048, &Vs[buf][wave * 1024 + 512]);
    };

    STAGEKV(0, 0);
    __syncthreads();

    for (int it = 0; it < 32; ++it) {
        int c0 = it * 64;
        int cur = it & 1;
        if (it < 31) STAGEKV(cur ^ 1, c0 + 64);

        unsigned mw[4][2];
        for (int t = 0; t < 4; t++) {
            uint2 m2 = *(const uint2*)&Pmf[it * 32 + 8 * t + 2 * lg];
            mw[t][0] = m2.x; mw[t][1] = m2.y;
        }
        f32x4 st[2][4];
        __builtin_amdgcn_s_setprio(1);
        for (int t = 0; t < 4; t++) {
            int row = t * 16 + lr;
            short8 kf0 = *(const short8*)&Ks[cur][row * 64 + rs0 * 8];
            short8 kf1 = *(const short8*)&Ks[cur][row * 64 + rs1 * 8];
            for (int sub = 0; sub < 2; sub++) {
                f32x4 z = (f32x4){0.f, 0.f, 0.f, 0.f};
                z = __builtin_amdgcn_mfma_f32_16x16x32_bf16(kf0, qa[sub][0], z, 0, 0, 0);
                z = __builtin_amdgcn_mfma_f32_16x16x32_bf16(kf1, qa[sub][1], z, 0, 0, 0);
                st[sub][t] = z;
            }
        }
        __builtin_amdgcn_s_setprio(0);
        short8 vf[2][4];
        for (int ks = 0; ks < 2; ks++) {
            int rsk = ks ? rs1 : rs0;
            for (int nt = 0; nt < 4; nt++)
                vf[ks][nt] = *(const short8*)&Vs[cur][(nt * 16 + lr) * 64 + rsk * 8];
        }
        for (int sub = 0; sub < 2; sub++) {
            for (int t = 0; t < 4; t++) {
                for (int rrh = 0; rrh < 2; rrh++) {
                    float plo = ex2(st[sub][t][2 * rrh]);
                    float phi = ex2(st[sub][t][2 * rrh + 1]);
                    unsigned w = cvtpk(plo, phi) & mw[t][rrh];
                    Plw[wave][(8 * t + 2 * lg + rrh) * 17 + lr] = w;
                }
            }
            __builtin_amdgcn_s_setprio(1);
            for (int ks = 0; ks < 2; ks++) {
                unsigned wu[4];
                for (int jj = 0; jj < 4; jj++)
                    wu[jj] = Plw[wave][(16 * ks + 4 * lg + jj) * 17 + lr];
                short8 pf;
                __builtin_memcpy(&pf, wu, 16);
                accL[sub] = __builtin_amdgcn_mfma_f32_16x16x32_bf16(ones, pf, accL[sub], 0, 0, 0);
                for (int nt = 0; nt < 4; nt++)
                    accT[sub][nt] = __builtin_amdgcn_mfma_f32_16x16x32_bf16(vf[ks][nt], pf, accT[sub][nt], 0, 0, 0);
            }
            __builtin_amdgcn_s_setprio(0);
        }
        __syncthreads();
    }

    for (int sub = 0; sub < 2; sub++) {
        float ls = accL[sub][0];
        float inv = (ls > 0.f) ? 1.f / ls : 0.f;
        ushort* op = ao + ((size_t)(b * 2048 + qt * 32 + sub * 16) * 1024) + h * 64;
        for (int nt = 0; nt < 4; nt++) {
            unsigned w0 = cvtpk(accT[sub][nt][0] * inv, accT[sub][nt][1] * inv);
            unsigned w1 = cvtpk(accT[sub][nt][2] * inv, accT[sub][nt][3] * inv);
            uint2 ov; ov.x = w0; ov.y = w1;
            *(uint2*)&op[lr * 1024 + 16 * nt + 4 * lg] = ov;
        }
    }
}

extern "C" void kernel_launch(void* const* d_in, const int* in_sizes, int n_in,
                              void* d_out, int out_size, void* d_ws, size_t ws_size,
                              hipStream_t stream) {
    (void)in_sizes; (void)n_in; (void)out_size; (void)ws_size;

    char* w = (char*)d_ws;
    const size_t MB = 1024 * 1024;
    ushort* xn  = (ushort*)(w + 0 * MB);
    ushort* qkv = (ushort*)(w + 8 * MB);
    ushort* vT  = (ushort*)(w + 32 * MB);
    ushort* x1  = (ushort*)(w + 40 * MB);
    ushort* x2n = (ushort*)(w + 48 * MB);
    ushort* gh  = (ushort*)(w + 8 * MB);    // overlays qkv+vT (dead post-attn)
    ushort* qkvw_c = (ushort*)(w + 64 * MB);
    ushort* projw_c= (ushort*)(w + 70 * MB);
    ushort* fc1w_c = (ushort*)(w + 72 * MB);
    ushort* fc2w_c = (ushort*)(w + 80 * MB);
    char* small = w + 88 * MB;
    ushort* ln1g_c = (ushort*)(small + 0 * 4096);
    ushort* ln1b_c = (ushort*)(small + 1 * 4096);
    ushort* qbias_c= (ushort*)(small + 2 * 4096);
    ushort* vbias_c= (ushort*)(small + 3 * 4096);
    ushort* projb_c= (ushort*)(small + 4 * 4096);
    ushort* ln2g_c = (ushort*)(small + 5 * 4096);
    ushort* ln2b_c = (ushort*)(small + 6 * 4096);
    ushort* fc1b_c = (ushort*)(small + 7 * 4096);
    ushort* fc2b_c = (ushort*)(small + 9 * 4096);
    unsigned char* mask_c = (unsigned char*)(small + 10 * 4096);
    int* flags = (int*)(small + 11 * 4096);
    ushort* ao = xn;

    detect_kernel<<<1, 256, 0, stream>>>((const ushort*)d_in[0],
                                         (const unsigned char*)d_in[1], flags);
    prep_kernel<<<8200, 256, 0, stream>>>(d_in[0], d_in[1], d_in[2], d_in[3], d_in[4],
                                          d_in[5], d_in[6], d_in[7], d_in[8], d_in[9],
                                          d_in[10], d_in[11], d_in[12], d_in[13], d_in[14],
                                          w, flags);

    ln_kernel<<<1024, 256, 0, stream>>>(d_in[0], ln1g_c, ln1b_c, xn, flags, 1);
    gemm_qkv<<<dim3(32, 24), 256, 0, stream>>>(xn, d_in[4], qkvw_c, 1024, qbias_c,
                                               vbias_c, vbias_c, qkv, nullptr, flags);
    vtrans_kernel<<<dim3(32, 32), 256, 0, stream>>>(qkv, vT);
    attn_kernel<<<512, 256, 0, stream>>>(qkv, vT, mask_c, ao);
    gemm_proj<<<dim3(32, 8), 256, 0, stream>>>(ao, d_in[7], projw_c, 1024, projb_c,
                                               d_in[0], nullptr, x1, nullptr, flags);
    ln_kernel<<<1024, 256, 0, stream>>>(x1, ln2g_c, ln2b_c, x2n, flags, 0);
    gemm_fc1<<<dim3(32, 32), 256, 0, stream>>>(x2n, d_in[11], fc1w_c, 1024, fc1b_c,
                                               fc1b_c, fc1b_c, d_out, gh, flags);
    gemm_fc2<<<dim3(32, 8), 256, 0, stream>>>(gh, d_in[13], fc2w_c, 4096, fc2b_c,
                                              x1, x1, d_out, nullptr, flags);
}